// Round 6
// baseline (1042.725 us; speedup 1.0000x reference)
//
#include <hip/hip_runtime.h>
#include <hip/hip_bf16.h>
#include <stdint.h>

#define B_ 4
#define H_ 8
#define N_ 8192
#define D_ 512
#define M_ 256
#define BH 32          // B_*H_
#define TOK 32768      // B_*N_
#define SCALE 0.125f
#define LN_EPS 1e-5f

using bf16x8 = __attribute__((ext_vector_type(8))) short;
using f32x4  = __attribute__((ext_vector_type(4))) float;
typedef unsigned short u16;
typedef unsigned int   u32;

__device__ __forceinline__ float bf2f(u16 h){ union{u32 u; float f;} x; x.u = ((u32)h)<<16; return x.f; }
__device__ __forceinline__ u16 f2bf(float f){ union{float f; u32 u;} x; x.f=f; u32 r = (x.u + 0x7fffu + ((x.u>>16)&1u))>>16; return (u16)r; }
__device__ __forceinline__ f32x4 mfma16(bf16x8 a, bf16x8 b, f32x4 c){
  return __builtin_amdgcn_mfma_f32_16x16x32_bf16(a, b, c, 0, 0, 0);
}
// global->LDS DMA: wave-uniform lds base, HW appends lane*16B; lane L <-> (row L>>2, col (L&3)*8) of a [16][32] bf16 chunk
__device__ __forceinline__ void stage16(const u16* g, u16* lds){
  __builtin_amdgcn_global_load_lds((const __attribute__((address_space(1))) unsigned int*)g,
                                   (__attribute__((address_space(3))) unsigned int*)lds, 16, 0, 0);
}

// ---------------- weights prep: transpose + bf16 cast ----------------
__global__ __launch_bounds__(256) void k_prep(const float* __restrict__ wqkv, const float* __restrict__ wout,
                                              u16* __restrict__ wqkvt, u16* __restrict__ woutt){
  int id = blockIdx.x*256 + threadIdx.x;
  for (int i = id; i < 1536*512; i += gridDim.x*256){ int c = i>>9, kk = i&511; wqkvt[i] = f2bf(wqkv[(size_t)kk*1536 + c]); }
  for (int i = id; i < 512*512;  i += gridDim.x*256){ int c = i>>9, kk = i&511; woutt[i] = f2bf(wout[(size_t)kk*512 + c]); }
}

// ---------------- layernorm (fp32 -> bf16) ----------------
__global__ __launch_bounds__(256) void k_ln(const float* __restrict__ x, const float* __restrict__ g,
                                            const float* __restrict__ bb, u16* __restrict__ xn){
  int row = blockIdx.x; int tid = threadIdx.x;
  const float* xr = x + (size_t)row*D_;
  float2 v = reinterpret_cast<const float2*>(xr)[tid];
  float s1 = v.x + v.y, s2 = v.x*v.x + v.y*v.y;
  for (int o=1;o<64;o<<=1){ s1 += __shfl_xor(s1,o); s2 += __shfl_xor(s2,o); }
  __shared__ float a1[4], a2[4];
  if ((tid&63)==0){ a1[tid>>6]=s1; a2[tid>>6]=s2; }
  __syncthreads();
  s1 = a1[0]+a1[1]+a1[2]+a1[3]; s2 = a2[0]+a2[1]+a2[2]+a2[3];
  float mu = s1*(1.f/D_);
  float var = s2*(1.f/D_) - mu*mu;
  float rs = rsqrtf(var + LN_EPS);
  float2 gg = reinterpret_cast<const float2*>(g)[tid];
  float2 b2 = reinterpret_cast<const float2*>(bb)[tid];
  u16 o0 = f2bf((v.x-mu)*rs*gg.x + b2.x);
  u16 o1 = f2bf((v.y-mu)*rs*gg.y + b2.y);
  reinterpret_cast<u32*>(xn + (size_t)row*D_)[tid] = (u32)o0 | ((u32)o1<<16);
}

// ---------------- QKV GEMM: m97 + dbuf + counted vmcnt ----------------
__global__ __launch_bounds__(256) void k_qkv(const u16* __restrict__ A, const u16* __restrict__ Bt,
    u16* __restrict__ q, u16* __restrict__ k, u16* __restrict__ vt){
  __shared__ __align__(16) u16 As[2][128*32];
  __shared__ __align__(16) u16 Bs[2][128*32];
  int m0 = blockIdx.x*128, n0 = blockIdx.y*128;
  int tid = threadIdx.x, lane = tid&63, wave = tid>>6;
  int wm = wave>>1, wn = wave&1;
  int lr = lane>>2, lc = (lane&3)*8;
  f32x4 acc[4][4];
  #pragma unroll
  for (int i=0;i<4;i++)
    #pragma unroll
    for (int j=0;j<4;j++) acc[i][j] = (f32x4)0.f;

  auto stage_tile = [&](int k0, int buf){
    #pragma unroll
    for (int i=0;i<2;i++){
      int c = wave + i*4;   // 16-row chunk
      stage16(&A [(size_t)(m0 + c*16 + lr)*512 + k0 + lc], &As[buf][c*16*32]);
      stage16(&Bt[(size_t)(n0 + c*16 + lr)*512 + k0 + lc], &Bs[buf][c*16*32]);
    }
  };
  stage_tile(0, 0);
  for (int it=0; it<16; it++){
    int cur = it&1;
    if (it<15){
      stage_tile((it+1)*32, cur^1);
      asm volatile("s_waitcnt vmcnt(4)" ::: "memory");
    } else {
      asm volatile("s_waitcnt vmcnt(0)" ::: "memory");
    }
    __syncthreads();
    bf16x8 a[4], b[4];
    #pragma unroll
    for (int mi=0;mi<4;mi++) a[mi] = *reinterpret_cast<const bf16x8*>(&As[cur][(wm*64+mi*16+(lane&15))*32 + (lane>>4)*8]);
    #pragma unroll
    for (int ni=0;ni<4;ni++) b[ni] = *reinterpret_cast<const bf16x8*>(&Bs[cur][(wn*64+ni*16+(lane&15))*32 + (lane>>4)*8]);
    #pragma unroll
    for (int mi=0;mi<4;mi++)
      #pragma unroll
      for (int ni=0;ni<4;ni++)
        acc[mi][ni] = mfma16(a[mi], b[ni], acc[mi][ni]);
    __syncthreads();
  }
  #pragma unroll
  for (int mi=0;mi<4;mi++){
    int gr0 = m0 + wm*64 + mi*16 + ((lane>>4)<<2);
    #pragma unroll
    for (int ni=0;ni<4;ni++){
      int gc = n0 + wn*64 + ni*16 + (lane&15);
      int t = gc>>9, wi = gc&511, h = wi>>6, d = wi&63;
      #pragma unroll
      for (int r=0;r<4;r++){
        int row = gr0 + r; int bq = row>>13, n = row & (N_-1);
        float val = acc[mi][ni][r];
        size_t bhh = (size_t)(bq*H_+h);
        if (t==0)      q[(bhh*N_ + n)*64 + d] = f2bf(val*SCALE);
        else if (t==1) k[(bhh*N_ + n)*64 + d] = f2bf(val);
        else           vt[(bhh*64 + d)*N_ + n] = f2bf(val);
      }
    }
  }
}

// ---------------- landmark means ----------------
__global__ __launch_bounds__(64) void k_land(const u16* __restrict__ q, const u16* __restrict__ k,
                                             u16* __restrict__ ql, u16* __restrict__ kl){
  int bh = blockIdx.x >> 8, j = blockIdx.x & 255, d = threadIdx.x;
  size_t base = ((size_t)bh*N_ + j*32)*64 + d;
  float sq=0.f, sk=0.f;
  #pragma unroll
  for (int i=0;i<32;i++){ sq += bf2f(q[base + (size_t)i*64]); sk += bf2f(k[base + (size_t)i*64]); }
  size_t o = ((size_t)bh*256 + j)*64 + d;
  ql[o] = f2bf(sq*(1.f/32.f)); kl[o] = f2bf(sk*(1.f/32.f));
}

// ---------------- attn2 = softmax(ql @ kl^T), also writes transpose ----------------
__global__ __launch_bounds__(256) void k_attn2(const u16* __restrict__ ql, const u16* __restrict__ kl,
                                               float* __restrict__ X, float* __restrict__ Xt){
  int bh = blockIdx.x >> 8, i = blockIdx.x & 255, j = threadIdx.x;
  __shared__ float qrow[64];
  __shared__ float red[256];
  if (j < 64) qrow[j] = bf2f(ql[((size_t)bh*256+i)*64 + j]);
  __syncthreads();
  const u16* kr = kl + ((size_t)bh*256 + j)*64;
  float s = 0.f;
  #pragma unroll
  for (int d=0; d<64; d++) s += qrow[d]*bf2f(kr[d]);
  red[j] = s; __syncthreads();
  for (int o=128;o>0;o>>=1){ if (j<o) red[j] = fmaxf(red[j], red[j+o]); __syncthreads(); }
  float mx = red[0]; __syncthreads();
  float e = __expf(s - mx);
  red[j] = e; __syncthreads();
  for (int o=128;o>0;o>>=1){ if (j<o) red[j] += red[j+o]; __syncthreads(); }
  float p = e / red[0];
  X [((size_t)bh*256+i)*256 + j] = p;
  Xt[((size_t)bh*256+j)*256 + i] = p;
}

// ---------------- pinv scale: 1/(max rowsum * max colsum) ----------------
__global__ __launch_bounds__(256) void k_pinvstats(const float* __restrict__ X, float* __restrict__ sc){
  int bh = blockIdx.x, t = threadIdx.x;
  const float* Xb = X + ((size_t)bh<<16);
  float cs=0.f, rs=0.f;
  for (int i=0;i<256;i++) cs += Xb[(size_t)i*256 + t];
  for (int j=0;j<256;j++) rs += Xb[(size_t)t*256 + j];
  __shared__ float r1[256], r2[256];
  r1[t]=cs; r2[t]=rs; __syncthreads();
  for (int o=128;o>0;o>>=1){ if (t<o){ r1[t]=fmaxf(r1[t],r1[t+o]); r2[t]=fmaxf(r2[t],r2[t+o]); } __syncthreads(); }
  if (t==0) sc[bh] = 1.f/(r1[0]*r2[0]);
}

// ---------------- pinv init: hi/lo split of X and Z0 (normal + transposed) ----------------
__global__ __launch_bounds__(256) void k_pinvinit(const float* __restrict__ X, const float* __restrict__ Xt,
     const float* __restrict__ sc, u16* Xhi, u16* Xlo, u16* Znhi, u16* Znlo, u16* Zthi, u16* Ztlo){
  size_t i = (size_t)blockIdx.x*256 + threadIdx.x;
  int bh = (int)(i>>16);
  float s = sc[bh];
  float xv = X[i];  u16 h1 = f2bf(xv);  Xhi[i]=h1;  Xlo[i]=f2bf(xv - bf2f(h1));
  float zn = Xt[i]*s; u16 h2 = f2bf(zn); Znhi[i]=h2; Znlo[i]=f2bf(zn - bf2f(h2));
  float zt = xv*s;  u16 h3 = f2bf(zt);  Zthi[i]=h3; Ztlo[i]=f2bf(zt - bf2f(h3));
}

// ---------------- batched 256^3 hi/lo-split MFMA matmul (dbuf + counted vmcnt) ----------------
template<int MODE>
__global__ __launch_bounds__(256) void k_mmhl(
    const u16* Ahi, const u16* Alo,
    const u16* Bthi, const u16* Btlo,
    u16* Chi, u16* Clo,
    const u16* Znhi, const u16* Znlo,
    const u16* B1hi, const u16* B1lo,
    const u16* B2hi, const u16* B2lo,
    u16* Zothi, u16* Zotlo)
{
  __shared__ __align__(16) u16 AhS[2][64*32];
  __shared__ __align__(16) u16 AlS[2][64*32];
  __shared__ __align__(16) u16 BhS[2][64*32];
  __shared__ __align__(16) u16 BlS[2][64*32];
  int bh = blockIdx.z;
  int m0 = blockIdx.x*64, n0 = blockIdx.y*64;
  size_t base = ((size_t)bh)<<16;
  int tid = threadIdx.x, lane = tid&63, wave = tid>>6;
  int wm = wave>>1, wn = wave&1;
  int lr = lane>>2, lc = (lane&3)*8;
  f32x4 acc[2][2];
  #pragma unroll
  for (int i=0;i<2;i++)
    #pragma unroll
    for (int j=0;j<2;j++) acc[i][j] = (f32x4)0.f;

  auto stage_tile = [&](int k0, int buf){
    stage16(&Ahi [base + (size_t)(m0 + wave*16 + lr)*256 + k0 + lc], &AhS[buf][wave*16*32]);
    stage16(&Alo [base + (size_t)(m0 + wave*16 + lr)*256 + k0 + lc], &AlS[buf][wave*16*32]);
    stage16(&Bthi[base + (size_t)(n0 + wave*16 + lr)*256 + k0 + lc], &BhS[buf][wave*16*32]);
    stage16(&Btlo[base + (size_t)(n0 + wave*16 + lr)*256 + k0 + lc], &BlS[buf][wave*16*32]);
  };
  stage_tile(0, 0);
  for (int it=0; it<8; it++){
    int cur = it&1;
    if (it<7){
      stage_tile((it+1)*32, cur^1);
      asm volatile("s_waitcnt vmcnt(4)" ::: "memory");
    } else {
      asm volatile("s_waitcnt vmcnt(0)" ::: "memory");
    }
    __syncthreads();
    bf16x8 ah[2], al2[2], bh2[2], bl2[2];
    #pragma unroll
    for (int mi=0;mi<2;mi++){
      int rr = wm*32 + mi*16 + (lane&15);
      ah[mi]  = *reinterpret_cast<const bf16x8*>(&AhS[cur][rr*32 + (lane>>4)*8]);
      al2[mi] = *reinterpret_cast<const bf16x8*>(&AlS[cur][rr*32 + (lane>>4)*8]);
    }
    #pragma unroll
    for (int ni=0;ni<2;ni++){
      int rr = wn*32 + ni*16 + (lane&15);
      bh2[ni] = *reinterpret_cast<const bf16x8*>(&BhS[cur][rr*32 + (lane>>4)*8]);
      bl2[ni] = *reinterpret_cast<const bf16x8*>(&BlS[cur][rr*32 + (lane>>4)*8]);
    }
    #pragma unroll
    for (int mi=0;mi<2;mi++)
      #pragma unroll
      for (int ni=0;ni<2;ni++){
        f32x4 c = acc[mi][ni];
        c = mfma16(ah[mi],  bh2[ni], c);
        c = mfma16(ah[mi],  bl2[ni], c);
        c = mfma16(al2[mi], bh2[ni], c);
        acc[mi][ni] = c;
      }
    __syncthreads();
  }
  #pragma unroll
  for (int mi=0;mi<2;mi++){
    #pragma unroll
    for (int ni=0;ni<2;ni++){
      int gr0 = m0 + wm*32 + mi*16 + ((lane>>4)<<2);
      int gc  = n0 + wn*32 + ni*16 + (lane&15);
      #pragma unroll
      for (int rr=0;rr<4;rr++){
        int gr = gr0 + rr;
        float val = acc[mi][ni][rr];
        if (MODE==0){
          size_t o = base + (size_t)gr*256 + gc;
          u16 hh = f2bf(val); Chi[o]=hh; Clo[o]=f2bf(val - bf2f(hh));
        } else if (MODE==1){
          size_t o = base + (size_t)gc*256 + gr;
          u16 hh = f2bf(val); Chi[o]=hh; Clo[o]=f2bf(val - bf2f(hh));
        } else {
          size_t o = base + (size_t)gr*256 + gc;
          float z  = bf2f(Znhi[o]) + bf2f(Znlo[o]);
          float b1 = bf2f(B1hi[o]) + bf2f(B1lo[o]);
          float b2 = bf2f(B2hi[o]) + bf2f(B2lo[o]);
          float zn = 0.25f*(13.f*z - 15.f*b1 + 7.f*b2 - val);
          u16 hh = f2bf(zn); u16 ll = f2bf(zn - bf2f(hh));
          Chi[o] = hh; Clo[o] = ll;
          size_t ot = base + (size_t)gc*256 + gr;
          Zothi[ot] = hh; Zotlo[ot] = ll;
        }
      }
    }
  }
}

// ---------------- fused sim3/exp/rowsum/(attn3@v): flash-style, k-split partials ----------------
__global__ __launch_bounds__(256) void k_flashw(const u16* __restrict__ ql, const u16* __restrict__ kb,
                                                const u16* __restrict__ vt,
                                                float* __restrict__ part, float* __restrict__ lpart){
  __shared__ __align__(16) u16 P[4][64][40];
  int kc = blockIdx.x, bh = blockIdx.y;   // kc in [0,16), 512-col chunk
  int tid = threadIdx.x, lane = tid&63, wave = tid>>6;
  bf16x8 aq[4][2];
  #pragma unroll
  for (int mi=0;mi<4;mi++){
    int row = wave*64 + mi*16 + (lane&15);
    #pragma unroll
    for (int ks=0;ks<2;ks++)
      aq[mi][ks] = *reinterpret_cast<const bf16x8*>(&ql[((size_t)bh*256 + row)*64 + ks*32 + (lane>>4)*8]);
  }
  f32x4 acc[4][4];
  float rs[4][4];
  #pragma unroll
  for (int i=0;i<4;i++)
    #pragma unroll
    for (int j=0;j<4;j++){ acc[i][j] = (f32x4)0.f; rs[i][j] = 0.f; }
  for (int step=0; step<16; step++){
    int nb = kc*512 + step*32;
    f32x4 s[4][2];
    #pragma unroll
    for (int ci=0;ci<2;ci++){
      int j = nb + ci*16 + (lane&15);
      const u16* kr = &kb[((size_t)bh*N_ + j)*64 + (lane>>4)*8];
      bf16x8 b0 = *reinterpret_cast<const bf16x8*>(kr);
      bf16x8 b1 = *reinterpret_cast<const bf16x8*>(kr + 32);
      #pragma unroll
      for (int mi=0;mi<4;mi++)
        s[mi][ci] = mfma16(aq[mi][1], b1, mfma16(aq[mi][0], b0, (f32x4)0.f));
    }
    #pragma unroll
    for (int mi=0;mi<4;mi++)
      #pragma unroll
      for (int ci=0;ci<2;ci++)
        #pragma unroll
        for (int rr=0;rr<4;rr++){
          float e = __expf(s[mi][ci][rr]);
          rs[mi][rr] += e;
          P[wave][mi*16 + ((lane>>4)<<2) + rr][ci*16 + (lane&15)] = f2bf(e);
        }
    __syncthreads();
    bf16x8 ap[4];
    #pragma unroll
    for (int mi=0;mi<4;mi++)
      ap[mi] = *reinterpret_cast<const bf16x8*>(&P[wave][mi*16 + (lane&15)][(lane>>4)*8]);
    #pragma unroll
    for (int ci=0;ci<4;ci++){
      int d = ci*16 + (lane&15);
      bf16x8 bv = *reinterpret_cast<const bf16x8*>(&vt[((size_t)bh*64 + d)*N_ + nb + (lane>>4)*8]);
      #pragma unroll
      for (int mi=0;mi<4;mi++)
        acc[mi][ci] = mfma16(ap[mi], bv, acc[mi][ci]);
    }
    __syncthreads();
  }
  #pragma unroll
  for (int mi=0;mi<4;mi++)
    #pragma unroll
    for (int rr=0;rr<4;rr++){
      float v2 = rs[mi][rr];
      v2 += __shfl_xor(v2,1); v2 += __shfl_xor(v2,2); v2 += __shfl_xor(v2,4); v2 += __shfl_xor(v2,8);
      rs[mi][rr] = v2;
    }
  size_t pb = ((size_t)kc*32 + bh)*256;
  #pragma unroll
  for (int mi=0;mi<4;mi++){
    int r0 = wave*64 + mi*16 + ((lane>>4)<<2);
    #pragma unroll
    for (int ci=0;ci<4;ci++){
      int d = ci*16 + (lane&15);
      #pragma unroll
      for (int rr=0;rr<4;rr++)
        part[(pb + r0 + rr)*64 + d] = acc[mi][ci][rr];
    }
    if ((lane&15)==0){
      #pragma unroll
      for (int rr=0;rr<4;rr++)
        lpart[pb + r0 + rr] = rs[mi][rr];
    }
  }
}

// ---------------- finish w = (sum partials)/(sum lpart) ----------------
__global__ __launch_bounds__(256) void k_wfin(const float* __restrict__ part, const float* __restrict__ lpart,
                                              float* __restrict__ w){
  int idx = blockIdx.x*256 + threadIdx.x;   // 524288
  int bh = idx>>14, within = idx & 16383, r = within>>6;
  float s = 0.f, l = 0.f;
  #pragma unroll
  for (int c=0;c<16;c++){
    s += part [(size_t)(c*32+bh)*16384 + within];
    l += lpart[(size_t)(c*32+bh)*256 + r];
  }
  w[idx] = s / l;
}

// ---------------- w2^T = (z @ w)^T, bf16 ----------------
__global__ __launch_bounds__(64) void k_w2(const u16* __restrict__ Zhi, const u16* __restrict__ Zlo,
                                           const float* __restrict__ w, u16* __restrict__ w2t){
  int bh = blockIdx.x>>8, j = blockIdx.x&255, d = threadIdx.x;
  size_t zb = ((size_t)bh<<16) + (size_t)j*256;
  float acc = 0.f;
  for (int i=0;i<256;i++){
    float zv = bf2f(Zhi[zb+i]) + bf2f(Zlo[zb+i]);
    acc += zv * w[((size_t)bh*256 + i)*64 + d];
  }
  w2t[((size_t)bh*64 + d)*256 + j] = f2bf(acc);
}

// ---------------- depthwise conv(33) along n: register sliding window, 8 outputs/thread ----------------
__global__ __launch_bounds__(256) void k_conv(const u16* __restrict__ vt, const float* __restrict__ kern,
                                              u16* __restrict__ res_t){
  int t = threadIdx.x;
  int d = blockIdx.y, bh = blockIdx.z;
  int n0 = blockIdx.x*2048 + t*8;
  const u16* src = vt + ((size_t)bh*64 + d)*N_;
  const float* kh = kern + (bh&7)*33;   // uniform per block -> scalar loads
  float xv[40];
  #pragma unroll
  for (int vv=0; vv<5; vv++){
    int nb = n0 - 16 + vv*8;
    if (nb >= 0 && nb + 8 <= N_) {
      bf16x8 raw = *reinterpret_cast<const bf16x8*>(src + nb);
      #pragma unroll
      for (int j=0;j<8;j++) xv[vv*8+j] = bf2f((u16)raw[j]);
    } else {
      #pragma unroll
      for (int j=0;j<8;j++){
        int n = nb + j;
        xv[vv*8+j] = (n>=0 && n<N_) ? bf2f(src[n]) : 0.f;
      }
    }
  }
  float c[33];
  #pragma unroll
  for (int kk2=0;kk2<33;kk2++) c[kk2] = kh[kk2];
  u16 outv[8];
  #pragma unroll
  for (int j=0;j<8;j++){
    float acc = 0.f;
    #pragma unroll
    for (int kk2=0;kk2<33;kk2++) acc += xv[j+kk2]*c[kk2];
    outv[j] = f2bf(acc);
  }
  *reinterpret_cast<bf16x8*>(res_t + ((size_t)bh*64 + d)*N_ + n0) = *reinterpret_cast<bf16x8*>(outv);
}

// ---------------- fused attn1: softmax(q@kl^T) @ w2 + res -> concat bf16 ----------------
__global__ __launch_bounds__(256) void k_attn1(const u16* __restrict__ q, const u16* __restrict__ kl,
   const u16* __restrict__ w2t, const u16* __restrict__ res_t, u16* __restrict__ cc)
{
  __shared__ __align__(16) u16 P[4][32][136];
  int n0 = blockIdx.x*128, bh = blockIdx.y;
  int tid = threadIdx.x, lane = tid&63, wave = tid>>6;
  int bq = bh>>3, h = bh&7;
  bf16x8 a[2][2];
  #pragma unroll
  for (int mi=0;mi<2;mi++){
    int n = n0 + wave*32 + mi*16 + (lane&15);
    #pragma unroll
    for (int ks=0;ks<2;ks++)
      a[mi][ks] = *reinterpret_cast<const bf16x8*>(&q[((size_t)bh*N_ + n)*64 + ks*32 + (lane>>4)*8]);
  }
  float rowsum[2][4];
  #pragma unroll
  for (int mi=0;mi<2;mi++)
    #pragma unroll
    for (int rr=0;rr<4;rr++) rowsum[mi][rr]=0.f;
  f32x4 acco[2][4];
  #pragma unroll
  for (int mi=0;mi<2;mi++)
    #pragma unroll
    for (int ci=0;ci<4;ci++) acco[mi][ci] = (f32x4)0.f;

  #pragma unroll
  for (int half=0; half<2; half++){
    f32x4 accs[2][8];
    #pragma unroll
    for (int mi=0;mi<2;mi++)
      #pragma unroll
      for (int ci=0;ci<8;ci++) accs[mi][ci] = (f32x4)0.f;
    #pragma unroll
    for (int ci=0;ci<8;ci++){
      int j = (half*8+ci)*16 + (lane&15);
      bf16x8 b0 = *reinterpret_cast<const bf16x8*>(&kl[((size_t)bh*256 + j)*64 + (lane>>4)*8]);
      bf16x8 b1 = *reinterpret_cast<const bf16x8*>(&kl[((size_t)bh*256 + j)*64 + 32 + (lane>>4)*8]);
      #pragma unroll
      for (int mi=0;mi<2;mi++){
        f32x4 c = accs[mi][ci];
        c = mfma16(a[mi][0], b0, c);
        c = mfma16(a[mi][1], b1, c);
        accs[mi][ci] = c;
      }
    }
    #pragma unroll
    for (int mi=0;mi<2;mi++)
      #pragma unroll
      for (int ci=0;ci<8;ci++)
        #pragma unroll
        for (int rr=0;rr<4;rr++){
          float e = __expf(accs[mi][ci][rr]);
          rowsum[mi][rr] += e;
          P[wave][mi*16 + ((lane>>4)<<2) + rr][ci*16 + (lane&15)] = f2bf(e);
        }
    __syncthreads();
    #pragma unroll
    for (int ks=0;ks<4;ks++){
      bf16x8 a2[2];
      #pragma unroll
      for (int mi=0;mi<2;mi++)
        a2[mi] = *reinterpret_cast<const bf16x8*>(&P[wave][mi*16 + (lane&15)][ks*32 + (lane>>4)*8]);
      #pragma unroll
      for (int ci=0;ci<4;ci++){
        bf16x8 b2 = *reinterpret_cast<const bf16x8*>(&w2t[((size_t)bh*64 + ci*16 + (lane&15))*256 + half*128 + ks*32 + (lane>>4)*8]);
        #pragma unroll
        for (int mi=0;mi<2;mi++)
          acco[mi][ci] = mfma16(a2[mi], b2, acco[mi][ci]);
      }
    }
    __syncthreads();
  }
  #pragma unroll
  for (int mi=0;mi<2;mi++)
    #pragma unroll
    for (int rr=0;rr<4;rr++){
      float s = rowsum[mi][rr];
      s += __shfl_xor(s,1); s += __shfl_xor(s,2); s += __shfl_xor(s,4); s += __shfl_xor(s,8);
      rowsum[mi][rr] = s;
    }
  #pragma unroll
  for (int mi=0;mi<2;mi++){
    int nb = n0 + wave*32 + mi*16 + ((lane>>4)<<2);
    #pragma unroll
    for (int ci=0;ci<4;ci++){
      int d = ci*16 + (lane&15);
      #pragma unroll
      for (int rr=0;rr<4;rr++){
        int n = nb + rr;
        float val = acco[mi][ci][rr] / rowsum[mi][rr];
        val += bf2f(res_t[((size_t)bh*64 + d)*N_ + n]);
        cc[((size_t)bq*N_ + n)*512 + h*64 + d] = f2bf(val);
      }
    }
  }
}

// ---------------- out = cc @ w_out + b_out + x (m97 + dbuf + counted vmcnt) ----------------
__global__ __launch_bounds__(256) void k_out(const u16* __restrict__ A, const u16* __restrict__ Bt,
     const float* __restrict__ bo, const float* __restrict__ x, float* __restrict__ out){
  __shared__ __align__(16) u16 As[2][128*32];
  __shared__ __align__(16) u16 Bs[2][128*32];
  int m0 = blockIdx.x*128, n0 = blockIdx.y*128;
  int tid = threadIdx.x, lane = tid&63, wave = tid>>6;
  int wm = wave>>1, wn = wave&1;
  int lr = lane>>2, lc = (lane&3)*8;
  f32x4 acc[4][4];
  #pragma unroll
  for (int i=0;i<4;i++)
    #pragma unroll
    for (int j=0;j<4;j++) acc[i][j] = (f32x4)0.f;

  auto stage_tile = [&](int k0, int buf){
    #pragma unroll
    for (int i=0;i<2;i++){
      int c = wave + i*4;
      stage16(&A [(size_t)(m0 + c*16 + lr)*512 + k0 + lc], &As[buf][c*16*32]);
      stage16(&Bt[(size_t)(n0 + c*16 + lr)*512 + k0 + lc], &Bs[buf][c*16*32]);
    }
  };
  stage_tile(0, 0);
  for (int it=0; it<16; it++){
    int cur = it&1;
    if (it<15){
      stage_tile((it+1)*32, cur^1);
      asm volatile("s_waitcnt vmcnt(4)" ::: "memory");
    } else {
      asm volatile("s_waitcnt vmcnt(0)" ::: "memory");
    }
    __syncthreads();
    bf16x8 a[4], b[4];
    #pragma unroll
    for (int mi=0;mi<4;mi++) a[mi] = *reinterpret_cast<const bf16x8*>(&As[cur][(wm*64+mi*16+(lane&15))*32 + (lane>>4)*8]);
    #pragma unroll
    for (int ni=0;ni<4;ni++) b[ni] = *reinterpret_cast<const bf16x8*>(&Bs[cur][(wn*64+ni*16+(lane&15))*32 + (lane>>4)*8]);
    #pragma unroll
    for (int mi=0;mi<4;mi++)
      #pragma unroll
      for (int ni=0;ni<4;ni++)
        acc[mi][ni] = mfma16(a[mi], b[ni], acc[mi][ni]);
    __syncthreads();
  }
  #pragma unroll
  for (int mi=0;mi<4;mi++){
    int gr0 = m0 + wm*64 + mi*16 + ((lane>>4)<<2);
    #pragma unroll
    for (int ni=0;ni<4;ni++){
      int gc = n0 + wn*64 + ni*16 + (lane&15);
      float bv = bo[gc];
      #pragma unroll
      for (int r=0;r<4;r++){
        int row = gr0 + r;
        out[(size_t)row*512 + gc] = acc[mi][ni][r] + bv + x[(size_t)row*512 + gc];
      }
    }
  }
}

extern "C" void kernel_launch(void* const* d_in, const int* in_sizes, int n_in,
                              void* d_out, int out_size, void* d_ws, size_t ws_size,
                              hipStream_t stream) {
  (void)in_sizes; (void)n_in; (void)out_size;
  const float* x     = (const float*)d_in[0];
  const float* ln_g  = (const float*)d_in[1];
  const float* ln_b  = (const float*)d_in[2];
  const float* w_qkv = (const float*)d_in[3];
  const float* w_out = (const float*)d_in[4];
  const float* b_out = (const float*)d_in[5];
  const float* res_k = (const float*)d_in[6];
  float* out = (float*)d_out;

  char* ws = (char*)d_ws;
  size_t off = 0;
  auto alloc = [&](size_t n)->char*{ char* r = ws + off; off += (n + 255) & ~(size_t)255; return r; };

  u16* xn     = (u16*)alloc((size_t)TOK*512*2);      // cc aliases this after k_qkv
  u16* cc     = xn;
  u16* wqkvt  = (u16*)alloc(1536*512*2);
  u16* woutt  = (u16*)alloc(512*512*2);
  u16* qb     = (u16*)alloc((size_t)BH*N_*64*2);
  u16* kb     = (u16*)alloc((size_t)BH*N_*64*2);
  u16* vt     = (u16*)alloc((size_t)BH*N_*64*2);
  u16* ql     = (u16*)alloc((size_t)BH*256*64*2);
  u16* kl     = (u16*)alloc((size_t)BH*256*64*2);
  float* X    = (float*)alloc((size_t)BH*65536*4);   // A1t aliases this after pinvinit
  float* Xt   = (float*)alloc((size_t)BH*65536*4);   // B1 aliases this after pinvinit
  float* sc   = (float*)alloc(32*4);
  u16* Xhi    = (u16*)alloc((size_t)BH*65536*2);
  u16* Xlo    = (u16*)alloc((size_t)BH*65536*2);
  u16* Znh    = (u16*)alloc((size_t)BH*65536*2);
  u16* Znl    = (u16*)alloc((size_t)BH*65536*2);
  u16* Zth    = (u16*)alloc((size_t)BH*65536*2);
  u16* Ztl    = (u16*)alloc((size_t)BH*65536*2);
  u16* B2h    = (u16*)alloc((size_t)BH*65536*2);
  u16* B2l    = (u16*)alloc((size_t)BH*65536*2);
  u16* res_t  = (u16*)alloc((size_t)BH*64*N_*2);
  size_t need = off;
  if (ws_size < need) return;   // diagnostic guard: clean fail instead of OOB abort

  u16* A1th = (u16*)X;
  u16* A1tl = (u16*)X + (size_t)BH*65536;
  u16* B1h  = (u16*)Xt;
  u16* B1l  = (u16*)Xt + (size_t)BH*65536;

  // scratch carved from d_out (fully overwritten by k_out at the end)
  char* ob = (char*)d_out;
  float* part  = (float*)(ob);                        // 16*32*256*64*4 = 33,554,432
  float* lpart = (float*)(ob + 33554432);             // 16*32*256*4   =    524,288
  float* wbuf  = (float*)(ob + 34078720);             // 32*256*64*4   =  2,097,152
  u16*   w2t   = (u16*)  (ob + 36175872);             // 32*64*256*2   =  1,048,576

  k_prep<<<dim3(512),256,0,stream>>>(w_qkv, w_out, wqkvt, woutt);
  k_ln<<<dim3(TOK),256,0,stream>>>(x, ln_g, ln_b, xn);
  k_qkv<<<dim3(256,12),256,0,stream>>>(xn, wqkvt, qb, kb, vt);
  k_land<<<dim3(8192),64,0,stream>>>(qb, kb, ql, kl);
  k_attn2<<<dim3(8192),256,0,stream>>>(ql, kl, X, Xt);
  k_pinvstats<<<dim3(32),256,0,stream>>>(X, sc);
  k_pinvinit<<<dim3(8192),256,0,stream>>>(X, Xt, sc, Xhi, Xlo, Znh, Znl, Zth, Ztl);

  dim3 gmm(4,4,32);
  for (int it=0; it<6; it++){
    // A1 = X @ Z   (written transposed)
    k_mmhl<1><<<gmm,256,0,stream>>>(Xhi,Xlo, Zth,Ztl, A1th,A1tl,
        nullptr,nullptr,nullptr,nullptr,nullptr,nullptr, nullptr,nullptr);
    // B1 = Z @ A1
    k_mmhl<0><<<gmm,256,0,stream>>>(Znh,Znl, A1th,A1tl, B1h,B1l,
        nullptr,nullptr,nullptr,nullptr,nullptr,nullptr, nullptr,nullptr);
    // B2 = B1 @ A1
    k_mmhl<0><<<gmm,256,0,stream>>>(B1h,B1l, A1th,A1tl, B2h,B2l,
        nullptr,nullptr,nullptr,nullptr,nullptr,nullptr, nullptr,nullptr);
    // z' = 0.25(13Z - 15B1 + 7B2 - B2@A1), Z updated in place (epilogue-local reads)
    k_mmhl<2><<<gmm,256,0,stream>>>(B2h,B2l, A1th,A1tl, Znh,Znl,
        Znh,Znl, B1h,B1l, B2h,B2l, Zth,Ztl);
  }

  k_flashw<<<dim3(16,32),256,0,stream>>>(ql, kb, vt, part, lpart);
  k_wfin<<<dim3(2048),256,0,stream>>>(part, lpart, wbuf);
  k_w2<<<dim3(8192),64,0,stream>>>(Znh, Znl, wbuf, w2t);
  k_conv<<<dim3(4,64,32),256,0,stream>>>(vt, res_k, res_t);
  k_attn1<<<dim3(64,32),256,0,stream>>>(qb, kl, w2t, res_t, cc);
  k_out<<<dim3(256,4),256,0,stream>>>(cc, woutt, b_out, x, out);
}

// Round 9
// 997.148 us; speedup vs baseline: 1.0457x; 1.0457x over previous
//
#include <hip/hip_runtime.h>
#include <hip/hip_bf16.h>
#include <stdint.h>

#define B_ 4
#define H_ 8
#define N_ 8192
#define D_ 512
#define M_ 256
#define BH 32          // B_*H_
#define TOK 32768      // B_*N_
#define SCALE 0.125f
#define LN_EPS 1e-5f

using bf16x8 = __attribute__((ext_vector_type(8))) short;
using f32x4  = __attribute__((ext_vector_type(4))) float;
typedef unsigned short u16;
typedef unsigned int   u32;

__device__ __forceinline__ float bf2f(u16 h){ union{u32 u; float f;} x; x.u = ((u32)h)<<16; return x.f; }
__device__ __forceinline__ u16 f2bf(float f){ union{float f; u32 u;} x; x.f=f; u32 r = (x.u + 0x7fffu + ((x.u>>16)&1u))>>16; return (u16)r; }
__device__ __forceinline__ f32x4 mfma16(bf16x8 a, bf16x8 b, f32x4 c){
  return __builtin_amdgcn_mfma_f32_16x16x32_bf16(a, b, c, 0, 0, 0);
}
// global->LDS DMA: wave-uniform lds base, HW appends lane*16B (row lane>>2, phys chunk lane&3 of [16][32] bf16 chunk)
__device__ __forceinline__ void stage16(const u16* g, u16* lds){
  __builtin_amdgcn_global_load_lds((const __attribute__((address_space(1))) unsigned int*)g,
                                   (__attribute__((address_space(3))) unsigned int*)lds, 16, 0, 0);
}
// bank-conflict swizzle: physical chunk p of row r holds logical chunk (p - (r>>1))&3.
// stage side: lane L (phys chunk L&3, row L>>2) must FETCH logical chunk ((L&3)-(L>>3))&3:
__device__ __forceinline__ int swz_src(int lane){ return (((lane&3) - (lane>>3)) & 3) * 8; }
// read side: logical chunk q of row r lives at phys chunk (q + (r>>1))&3:
__device__ __forceinline__ int swz_ld(int row, int q){ return row*32 + (((q + (row>>1)) & 3) * 8); }

// ---------------- weights prep: transpose + bf16 cast ----------------
__global__ __launch_bounds__(256) void k_prep(const float* __restrict__ wqkv, const float* __restrict__ wout,
                                              u16* __restrict__ wqkvt, u16* __restrict__ woutt){
  int id = blockIdx.x*256 + threadIdx.x;
  for (int i = id; i < 1536*512; i += gridDim.x*256){ int c = i>>9, kk = i&511; wqkvt[i] = f2bf(wqkv[(size_t)kk*1536 + c]); }
  for (int i = id; i < 512*512;  i += gridDim.x*256){ int c = i>>9, kk = i&511; woutt[i] = f2bf(wout[(size_t)kk*512 + c]); }
}

// ---------------- layernorm (fp32 -> bf16) ----------------
__global__ __launch_bounds__(256) void k_ln(const float* __restrict__ x, const float* __restrict__ g,
                                            const float* __restrict__ bb, u16* __restrict__ xn){
  int row = blockIdx.x; int tid = threadIdx.x;
  const float* xr = x + (size_t)row*D_;
  float2 v = reinterpret_cast<const float2*>(xr)[tid];
  float s1 = v.x + v.y, s2 = v.x*v.x + v.y*v.y;
  for (int o=1;o<64;o<<=1){ s1 += __shfl_xor(s1,o); s2 += __shfl_xor(s2,o); }
  __shared__ float a1[4], a2[4];
  if ((tid&63)==0){ a1[tid>>6]=s1; a2[tid>>6]=s2; }
  __syncthreads();
  s1 = a1[0]+a1[1]+a1[2]+a1[3]; s2 = a2[0]+a2[1]+a2[2]+a2[3];
  float mu = s1*(1.f/D_);
  float var = s2*(1.f/D_) - mu*mu;
  float rs = rsqrtf(var + LN_EPS);
  float2 gg = reinterpret_cast<const float2*>(g)[tid];
  float2 b2 = reinterpret_cast<const float2*>(bb)[tid];
  u16 o0 = f2bf((v.x-mu)*rs*gg.x + b2.x);
  u16 o1 = f2bf((v.y-mu)*rs*gg.y + b2.y);
  reinterpret_cast<u32*>(xn + (size_t)row*D_)[tid] = (u32)o0 | ((u32)o1<<16);
}

// ---------------- QKV GEMM: m97 + swizzle + depth-3 pipeline ----------------
__global__ __launch_bounds__(256) void k_qkv(const u16* __restrict__ A, const u16* __restrict__ Bt,
    u16* __restrict__ q, u16* __restrict__ k, u16* __restrict__ vt){
  __shared__ __align__(16) u16 As[3][128*32];
  __shared__ __align__(16) u16 Bs[3][128*32];
  int m0 = blockIdx.x*128, n0 = blockIdx.y*128;
  int tid = threadIdx.x, lane = tid&63, wave = tid>>6;
  int wm = wave>>1, wn = wave&1;
  int lr = lane>>2, lcs = swz_src(lane);
  f32x4 acc[4][4];
  #pragma unroll
  for (int i=0;i<4;i++)
    #pragma unroll
    for (int j=0;j<4;j++) acc[i][j] = (f32x4)0.f;

  auto stage_tile = [&](int k0, int buf){
    #pragma unroll
    for (int i=0;i<2;i++){
      int c = wave + i*4;   // 16-row chunk
      stage16(&A [(size_t)(m0 + c*16 + lr)*512 + k0 + lcs], &As[buf][c*16*32]);
      stage16(&Bt[(size_t)(n0 + c*16 + lr)*512 + k0 + lcs], &Bs[buf][c*16*32]);
    }
  };
  stage_tile(0, 0);
  stage_tile(32, 1);
  for (int it=0; it<16; it++){
    int cur = it%3;
    if (it<14){
      stage_tile((it+2)*32, (it+2)%3);
      asm volatile("s_waitcnt vmcnt(8)" ::: "memory");
    } else if (it==14){
      asm volatile("s_waitcnt vmcnt(4)" ::: "memory");
    } else {
      asm volatile("s_waitcnt vmcnt(0)" ::: "memory");
    }
    __syncthreads();
    bf16x8 a[4], b[4];
    #pragma unroll
    for (int mi=0;mi<4;mi++) a[mi] = *reinterpret_cast<const bf16x8*>(&As[cur][swz_ld(wm*64+mi*16+(lane&15), lane>>4)]);
    #pragma unroll
    for (int ni=0;ni<4;ni++) b[ni] = *reinterpret_cast<const bf16x8*>(&Bs[cur][swz_ld(wn*64+ni*16+(lane&15), lane>>4)]);
    #pragma unroll
    for (int mi=0;mi<4;mi++)
      #pragma unroll
      for (int ni=0;ni<4;ni++)
        acc[mi][ni] = mfma16(a[mi], b[ni], acc[mi][ni]);
    __syncthreads();
  }
  #pragma unroll
  for (int mi=0;mi<4;mi++){
    int gr0 = m0 + wm*64 + mi*16 + ((lane>>4)<<2);
    #pragma unroll
    for (int ni=0;ni<4;ni++){
      int gc = n0 + wn*64 + ni*16 + (lane&15);
      int t = gc>>9, wi = gc&511, h = wi>>6, d = wi&63;
      size_t bhh0 = (size_t)((gr0>>13)*H_ + h);
      if (t==2){
        u16 pk[4];
        #pragma unroll
        for (int r=0;r<4;r++) pk[r] = f2bf(acc[mi][ni][r]);
        int n = gr0 & (N_-1);
        *reinterpret_cast<uint2*>(&vt[(bhh0*64 + d)*N_ + n]) = *reinterpret_cast<const uint2*>(pk);
      } else {
        #pragma unroll
        for (int r=0;r<4;r++){
          int row = gr0 + r; int n = row & (N_-1);
          float val = acc[mi][ni][r];
          if (t==0)      q[(bhh0*N_ + n)*64 + d] = f2bf(val*SCALE);
          else           k[(bhh0*N_ + n)*64 + d] = f2bf(val);
        }
      }
    }
  }
}

// ---------------- landmark means ----------------
__global__ __launch_bounds__(64) void k_land(const u16* __restrict__ q, const u16* __restrict__ k,
                                             u16* __restrict__ ql, u16* __restrict__ kl){
  int bh = blockIdx.x >> 8, j = blockIdx.x & 255, d = threadIdx.x;
  size_t base = ((size_t)bh*N_ + j*32)*64 + d;
  float sq=0.f, sk=0.f;
  #pragma unroll
  for (int i=0;i<32;i++){ sq += bf2f(q[base + (size_t)i*64]); sk += bf2f(k[base + (size_t)i*64]); }
  size_t o = ((size_t)bh*256 + j)*64 + d;
  ql[o] = f2bf(sq*(1.f/32.f)); kl[o] = f2bf(sk*(1.f/32.f));
}

// ---------------- attn2 = softmax(ql @ kl^T), also writes transpose ----------------
__global__ __launch_bounds__(256) void k_attn2(const u16* __restrict__ ql, const u16* __restrict__ kl,
                                               float* __restrict__ X, float* __restrict__ Xt){
  int bh = blockIdx.x >> 8, i = blockIdx.x & 255, j = threadIdx.x;
  __shared__ float qrow[64];
  __shared__ float red[256];
  if (j < 64) qrow[j] = bf2f(ql[((size_t)bh*256+i)*64 + j]);
  __syncthreads();
  const u16* kr = kl + ((size_t)bh*256 + j)*64;
  float s = 0.f;
  #pragma unroll
  for (int d=0; d<64; d++) s += qrow[d]*bf2f(kr[d]);
  red[j] = s; __syncthreads();
  for (int o=128;o>0;o>>=1){ if (j<o) red[j] = fmaxf(red[j], red[j+o]); __syncthreads(); }
  float mx = red[0]; __syncthreads();
  float e = __expf(s - mx);
  red[j] = e; __syncthreads();
  for (int o=128;o>0;o>>=1){ if (j<o) red[j] += red[j+o]; __syncthreads(); }
  float p = e / red[0];
  X [((size_t)bh*256+i)*256 + j] = p;
  Xt[((size_t)bh*256+j)*256 + i] = p;
}

// ---------------- pinv scale: 1/(max rowsum * max colsum) ----------------
__global__ __launch_bounds__(256) void k_pinvstats(const float* __restrict__ X, float* __restrict__ sc){
  int bh = blockIdx.x, t = threadIdx.x;
  const float* Xb = X + ((size_t)bh<<16);
  float cs=0.f, rs=0.f;
  for (int i=0;i<256;i++) cs += Xb[(size_t)i*256 + t];
  for (int j=0;j<256;j++) rs += Xb[(size_t)t*256 + j];
  __shared__ float r1[256], r2[256];
  r1[t]=cs; r2[t]=rs; __syncthreads();
  for (int o=128;o>0;o>>=1){ if (t<o){ r1[t]=fmaxf(r1[t],r1[t+o]); r2[t]=fmaxf(r2[t],r2[t+o]); } __syncthreads(); }
  if (t==0) sc[bh] = 1.f/(r1[0]*r2[0]);
}

// ---------------- pinv init: hi/lo split of X and Z0 (normal + transposed) ----------------
__global__ __launch_bounds__(256) void k_pinvinit(const float* __restrict__ X, const float* __restrict__ Xt,
     const float* __restrict__ sc, u16* Xhi, u16* Xlo, u16* Znhi, u16* Znlo, u16* Zthi, u16* Ztlo){
  size_t i = (size_t)blockIdx.x*256 + threadIdx.x;
  int bh = (int)(i>>16);
  float s = sc[bh];
  float xv = X[i];  u16 h1 = f2bf(xv);  Xhi[i]=h1;  Xlo[i]=f2bf(xv - bf2f(h1));
  float zn = Xt[i]*s; u16 h2 = f2bf(zn); Znhi[i]=h2; Znlo[i]=f2bf(zn - bf2f(h2));
  float zt = xv*s;  u16 h3 = f2bf(zt);  Zthi[i]=h3; Ztlo[i]=f2bf(zt - bf2f(h3));
}

// ---------------- batched 256^3 hi/lo MFMA matmul (swizzle + depth-3) ----------------
template<int MODE>
__global__ __launch_bounds__(256) void k_mmhl(
    const u16* Ahi, const u16* Alo,
    const u16* Bthi, const u16* Btlo,
    u16* Chi, u16* Clo,
    const u16* Znhi, const u16* Znlo,
    const u16* B1hi, const u16* B1lo,
    const u16* B2hi, const u16* B2lo,
    u16* Zothi, u16* Zotlo)
{
  __shared__ __align__(16) u16 AhS[3][64*32];
  __shared__ __align__(16) u16 AlS[3][64*32];
  __shared__ __align__(16) u16 BhS[3][64*32];
  __shared__ __align__(16) u16 BlS[3][64*32];
  int bh = blockIdx.z;
  int m0 = blockIdx.x*64, n0 = blockIdx.y*64;
  size_t base = ((size_t)bh)<<16;
  int tid = threadIdx.x, lane = tid&63, wave = tid>>6;
  int wm = wave>>1, wn = wave&1;
  int lr = lane>>2, lcs = swz_src(lane);
  f32x4 acc[2][2];
  #pragma unroll
  for (int i=0;i<2;i++)
    #pragma unroll
    for (int j=0;j<2;j++) acc[i][j] = (f32x4)0.f;

  auto stage_tile = [&](int k0, int buf){
    stage16(&Ahi [base + (size_t)(m0 + wave*16 + lr)*256 + k0 + lcs], &AhS[buf][wave*16*32]);
    stage16(&Alo [base + (size_t)(m0 + wave*16 + lr)*256 + k0 + lcs], &AlS[buf][wave*16*32]);
    stage16(&Bthi[base + (size_t)(n0 + wave*16 + lr)*256 + k0 + lcs], &BhS[buf][wave*16*32]);
    stage16(&Btlo[base + (size_t)(n0 + wave*16 + lr)*256 + k0 + lcs], &BlS[buf][wave*16*32]);
  };
  stage_tile(0, 0);
  stage_tile(32, 1);
  for (int it=0; it<8; it++){
    int cur = it%3;
    if (it<6){
      stage_tile((it+2)*32, (it+2)%3);
      asm volatile("s_waitcnt vmcnt(8)" ::: "memory");
    } else if (it==6){
      asm volatile("s_waitcnt vmcnt(4)" ::: "memory");
    } else {
      asm volatile("s_waitcnt vmcnt(0)" ::: "memory");
    }
    __syncthreads();
    bf16x8 ah[2], al2[2], bh2[2], bl2[2];
    #pragma unroll
    for (int mi=0;mi<2;mi++){
      int rr = wm*32 + mi*16 + (lane&15);
      ah[mi]  = *reinterpret_cast<const bf16x8*>(&AhS[cur][swz_ld(rr, lane>>4)]);
      al2[mi] = *reinterpret_cast<const bf16x8*>(&AlS[cur][swz_ld(rr, lane>>4)]);
    }
    #pragma unroll
    for (int ni=0;ni<2;ni++){
      int rr = wn*32 + ni*16 + (lane&15);
      bh2[ni] = *reinterpret_cast<const bf16x8*>(&BhS[cur][swz_ld(rr, lane>>4)]);
      bl2[ni] = *reinterpret_cast<const bf16x8*>(&BlS[cur][swz_ld(rr, lane>>4)]);
    }
    #pragma unroll
    for (int mi=0;mi<2;mi++)
      #pragma unroll
      for (int ni=0;ni<2;ni++){
        f32x4 c = acc[mi][ni];
        c = mfma16(ah[mi],  bh2[ni], c);
        c = mfma16(ah[mi],  bl2[ni], c);
        c = mfma16(al2[mi], bh2[ni], c);
        acc[mi][ni] = c;
      }
    __syncthreads();
  }
  #pragma unroll
  for (int mi=0;mi<2;mi++){
    #pragma unroll
    for (int ni=0;ni<2;ni++){
      int gr0 = m0 + wm*32 + mi*16 + ((lane>>4)<<2);
      int gc  = n0 + wn*32 + ni*16 + (lane&15);
      #pragma unroll
      for (int rr=0;rr<4;rr++){
        int gr = gr0 + rr;
        float val = acc[mi][ni][rr];
        if (MODE==0){
          size_t o = base + (size_t)gr*256 + gc;
          u16 hh = f2bf(val); Chi[o]=hh; Clo[o]=f2bf(val - bf2f(hh));
        } else if (MODE==1){
          size_t o = base + (size_t)gc*256 + gr;
          u16 hh = f2bf(val); Chi[o]=hh; Clo[o]=f2bf(val - bf2f(hh));
        } else {
          size_t o = base + (size_t)gr*256 + gc;
          float z  = bf2f(Znhi[o]) + bf2f(Znlo[o]);
          float b1 = bf2f(B1hi[o]) + bf2f(B1lo[o]);
          float b2 = bf2f(B2hi[o]) + bf2f(B2lo[o]);
          float zn = 0.25f*(13.f*z - 15.f*b1 + 7.f*b2 - val);
          u16 hh = f2bf(zn); u16 ll = f2bf(zn - bf2f(hh));
          Chi[o] = hh; Clo[o] = ll;
          size_t ot = base + (size_t)gc*256 + gr;
          Zothi[ot] = hh; Zotlo[ot] = ll;
        }
      }
    }
  }
}

// ---------------- fused sim3/exp/rowsum/(attn3@v): flash-style, k-split partials ----------------
__global__ __launch_bounds__(256) void k_flashw(const u16* __restrict__ ql, const u16* __restrict__ kb,
                                                const u16* __restrict__ vt,
                                                float* __restrict__ part, float* __restrict__ lpart){
  __shared__ __align__(16) u16 P[4][64][40];
  int kc = blockIdx.x, bh = blockIdx.y;   // kc in [0,16), 512-col chunk
  int tid = threadIdx.x, lane = tid&63, wave = tid>>6;
  bf16x8 aq[4][2];
  #pragma unroll
  for (int mi=0;mi<4;mi++){
    int row = wave*64 + mi*16 + (lane&15);
    #pragma unroll
    for (int ks=0;ks<2;ks++)
      aq[mi][ks] = *reinterpret_cast<const bf16x8*>(&ql[((size_t)bh*256 + row)*64 + ks*32 + (lane>>4)*8]);
  }
  f32x4 acc[4][4];
  float rs[4][4];
  #pragma unroll
  for (int i=0;i<4;i++)
    #pragma unroll
    for (int j=0;j<4;j++){ acc[i][j] = (f32x4)0.f; rs[i][j] = 0.f; }
  for (int step=0; step<16; step++){
    int nb = kc*512 + step*32;
    f32x4 s[4][2];
    #pragma unroll
    for (int ci=0;ci<2;ci++){
      int j = nb + ci*16 + (lane&15);
      const u16* kr = &kb[((size_t)bh*N_ + j)*64 + (lane>>4)*8];
      bf16x8 b0 = *reinterpret_cast<const bf16x8*>(kr);
      bf16x8 b1 = *reinterpret_cast<const bf16x8*>(kr + 32);
      #pragma unroll
      for (int mi=0;mi<4;mi++)
        s[mi][ci] = mfma16(aq[mi][1], b1, mfma16(aq[mi][0], b0, (f32x4)0.f));
    }
    #pragma unroll
    for (int mi=0;mi<4;mi++)
      #pragma unroll
      for (int ci=0;ci<2;ci++)
        #pragma unroll
        for (int rr=0;rr<4;rr++){
          float e = __expf(s[mi][ci][rr]);
          rs[mi][rr] += e;
          P[wave][mi*16 + ((lane>>4)<<2) + rr][ci*16 + (lane&15)] = f2bf(e);
        }
    __syncthreads();
    bf16x8 ap[4];
    #pragma unroll
    for (int mi=0;mi<4;mi++)
      ap[mi] = *reinterpret_cast<const bf16x8*>(&P[wave][mi*16 + (lane&15)][(lane>>4)*8]);
    #pragma unroll
    for (int ci=0;ci<4;ci++){
      int d = ci*16 + (lane&15);
      bf16x8 bv = *reinterpret_cast<const bf16x8*>(&vt[((size_t)bh*64 + d)*N_ + nb + (lane>>4)*8]);
      #pragma unroll
      for (int mi=0;mi<4;mi++)
        acc[mi][ci] = mfma16(ap[mi], bv, acc[mi][ci]);
    }
    __syncthreads();
  }
  #pragma unroll
  for (int mi=0;mi<4;mi++)
    #pragma unroll
    for (int rr=0;rr<4;rr++){
      float v2 = rs[mi][rr];
      v2 += __shfl_xor(v2,1); v2 += __shfl_xor(v2,2); v2 += __shfl_xor(v2,4); v2 += __shfl_xor(v2,8);
      rs[mi][rr] = v2;
    }
  size_t pb = ((size_t)kc*32 + bh)*256;
  #pragma unroll
  for (int mi=0;mi<4;mi++){
    int r0 = wave*64 + mi*16 + ((lane>>4)<<2);
    #pragma unroll
    for (int ci=0;ci<4;ci++){
      int d = ci*16 + (lane&15);
      #pragma unroll
      for (int rr=0;rr<4;rr++)
        part[(pb + r0 + rr)*64 + d] = acc[mi][ci][rr];
    }
    if ((lane&15)==0){
      #pragma unroll
      for (int rr=0;rr<4;rr++)
        lpart[pb + r0 + rr] = rs[mi][rr];
    }
  }
}

// ---------------- finish w = (sum partials)/(sum lpart) ----------------
__global__ __launch_bounds__(256) void k_wfin(const float* __restrict__ part, const float* __restrict__ lpart,
                                              float* __restrict__ w){
  int idx = blockIdx.x*256 + threadIdx.x;   // 524288
  int bh = idx>>14, within = idx & 16383, r = within>>6;
  float s = 0.f, l = 0.f;
  #pragma unroll
  for (int c=0;c<16;c++){
    s += part [(size_t)(c*32+bh)*16384 + within];
    l += lpart[(size_t)(c*32+bh)*256 + r];
  }
  w[idx] = s / l;
}

// ---------------- w2^T = (z @ w)^T, bf16 ----------------
__global__ __launch_bounds__(64) void k_w2(const u16* __restrict__ Zhi, const u16* __restrict__ Zlo,
                                           const float* __restrict__ w, u16* __restrict__ w2t){
  int bh = blockIdx.x>>8, j = blockIdx.x&255, d = threadIdx.x;
  size_t zb = ((size_t)bh<<16) + (size_t)j*256;
  float acc = 0.f;
  for (int i=0;i<256;i++){
    float zv = bf2f(Zhi[zb+i]) + bf2f(Zlo[zb+i]);
    acc += zv * w[((size_t)bh*256 + i)*64 + d];
  }
  w2t[((size_t)bh*64 + d)*256 + j] = f2bf(acc);
}

// ---------------- depthwise conv(33) along n: register sliding window, 8 outputs/thread ----------------
__global__ __launch_bounds__(256) void k_conv(const u16* __restrict__ vt, const float* __restrict__ kern,
                                              u16* __restrict__ res_t){
  int t = threadIdx.x;
  int d = blockIdx.y, bh = blockIdx.z;
  int n0 = blockIdx.x*2048 + t*8;
  const u16* src = vt + ((size_t)bh*64 + d)*N_;
  const float* kh = kern + (bh&7)*33;   // uniform per block -> scalar loads
  float xv[40];
  #pragma unroll
  for (int vv=0; vv<5; vv++){
    int nb = n0 - 16 + vv*8;
    if (nb >= 0 && nb + 8 <= N_) {
      bf16x8 raw = *reinterpret_cast<const bf16x8*>(src + nb);
      #pragma unroll
      for (int j=0;j<8;j++) xv[vv*8+j] = bf2f((u16)raw[j]);
    } else {
      #pragma unroll
      for (int j=0;j<8;j++){
        int n = nb + j;
        xv[vv*8+j] = (n>=0 && n<N_) ? bf2f(src[n]) : 0.f;
      }
    }
  }
  float c[33];
  #pragma unroll
  for (int kk2=0;kk2<33;kk2++) c[kk2] = kh[kk2];
  u16 outv[8];
  #pragma unroll
  for (int j=0;j<8;j++){
    float acc = 0.f;
    #pragma unroll
    for (int kk2=0;kk2<33;kk2++) acc += xv[j+kk2]*c[kk2];
    outv[j] = f2bf(acc);
  }
  *reinterpret_cast<bf16x8*>(res_t + ((size_t)bh*64 + d)*N_ + n0) = *reinterpret_cast<bf16x8*>(outv);
}

// ---------------- fused attn1: softmax(q@kl^T) @ w2 + res -> concat bf16 ----------------
__global__ __launch_bounds__(256) void k_attn1(const u16* __restrict__ q, const u16* __restrict__ kl,
   const u16* __restrict__ w2t, const u16* __restrict__ res_t, u16* __restrict__ cc)
{
  __shared__ __align__(16) u16 P[4][32][136];
  int n0 = blockIdx.x*128, bh = blockIdx.y;
  int tid = threadIdx.x, lane = tid&63, wave = tid>>6;
  int bq = bh>>3, h = bh&7;
  bf16x8 a[2][2];
  #pragma unroll
  for (int mi=0;mi<2;mi++){
    int n = n0 + wave*32 + mi*16 + (lane&15);
    #pragma unroll
    for (int ks=0;ks<2;ks++)
      a[mi][ks] = *reinterpret_cast<const bf16x8*>(&q[((size_t)bh*N_ + n)*64 + ks*32 + (lane>>4)*8]);
  }
  float rowsum[2][4];
  #pragma unroll
  for (int mi=0;mi<2;mi++)
    #pragma unroll
    for (int rr=0;rr<4;rr++) rowsum[mi][rr]=0.f;
  f32x4 acco[2][4];
  #pragma unroll
  for (int mi=0;mi<2;mi++)
    #pragma unroll
    for (int ci=0;ci<4;ci++) acco[mi][ci] = (f32x4)0.f;

  #pragma unroll
  for (int half=0; half<2; half++){
    f32x4 accs[2][8];
    #pragma unroll
    for (int mi=0;mi<2;mi++)
      #pragma unroll
      for (int ci=0;ci<8;ci++) accs[mi][ci] = (f32x4)0.f;
    #pragma unroll
    for (int ci=0;ci<8;ci++){
      int j = (half*8+ci)*16 + (lane&15);
      bf16x8 b0 = *reinterpret_cast<const bf16x8*>(&kl[((size_t)bh*256 + j)*64 + (lane>>4)*8]);
      bf16x8 b1 = *reinterpret_cast<const bf16x8*>(&kl[((size_t)bh*256 + j)*64 + 32 + (lane>>4)*8]);
      #pragma unroll
      for (int mi=0;mi<2;mi++){
        f32x4 c = accs[mi][ci];
        c = mfma16(a[mi][0], b0, c);
        c = mfma16(a[mi][1], b1, c);
        accs[mi][ci] = c;
      }
    }
    #pragma unroll
    for (int mi=0;mi<2;mi++)
      #pragma unroll
      for (int ci=0;ci<8;ci++)
        #pragma unroll
        for (int rr=0;rr<4;rr++){
          float e = __expf(accs[mi][ci][rr]);
          rowsum[mi][rr] += e;
          P[wave][mi*16 + ((lane>>4)<<2) + rr][ci*16 + (lane&15)] = f2bf(e);
        }
    __syncthreads();
    #pragma unroll
    for (int ks=0;ks<4;ks++){
      bf16x8 a2[2];
      #pragma unroll
      for (int mi=0;mi<2;mi++)
        a2[mi] = *reinterpret_cast<const bf16x8*>(&P[wave][mi*16 + (lane&15)][ks*32 + (lane>>4)*8]);
      #pragma unroll
      for (int ci=0;ci<4;ci++){
        bf16x8 b2 = *reinterpret_cast<const bf16x8*>(&w2t[((size_t)bh*64 + ci*16 + (lane&15))*256 + half*128 + ks*32 + (lane>>4)*8]);
        #pragma unroll
        for (int mi=0;mi<2;mi++)
          acco[mi][ci] = mfma16(a2[mi], b2, acco[mi][ci]);
      }
    }
    __syncthreads();
  }
  #pragma unroll
  for (int mi=0;mi<2;mi++)
    #pragma unroll
    for (int rr=0;rr<4;rr++){
      float s = rowsum[mi][rr];
      s += __shfl_xor(s,1); s += __shfl_xor(s,2); s += __shfl_xor(s,4); s += __shfl_xor(s,8);
      rowsum[mi][rr] = s;
    }
  #pragma unroll
  for (int mi=0;mi<2;mi++){
    int nb = n0 + wave*32 + mi*16 + ((lane>>4)<<2);
    #pragma unroll
    for (int ci=0;ci<4;ci++){
      int d = ci*16 + (lane&15);
      #pragma unroll
      for (int rr=0;rr<4;rr++){
        int n = nb + rr;
        float val = acco[mi][ci][rr] / rowsum[mi][rr];
        val += bf2f(res_t[((size_t)bh*64 + d)*N_ + n]);
        cc[((size_t)bq*N_ + n)*512 + h*64 + d] = f2bf(val);
      }
    }
  }
}

// ---------------- out = cc @ w_out + b_out + x (swizzle + depth-3) ----------------
__global__ __launch_bounds__(256) void k_out(const u16* __restrict__ A, const u16* __restrict__ Bt,
     const float* __restrict__ bo, const float* __restrict__ x, float* __restrict__ out){
  __shared__ __align__(16) u16 As[3][128*32];
  __shared__ __align__(16) u16 Bs[3][128*32];
  int m0 = blockIdx.x*128, n0 = blockIdx.y*128;
  int tid = threadIdx.x, lane = tid&63, wave = tid>>6;
  int wm = wave>>1, wn = wave&1;
  int lr = lane>>2, lcs = swz_src(lane);
  f32x4 acc[4][4];
  #pragma unroll
  for (int i=0;i<4;i++)
    #pragma unroll
    for (int j=0;j<4;j++) acc[i][j] = (f32x4)0.f;

  auto stage_tile = [&](int k0, int buf){
    #pragma unroll
    for (int i=0;i<2;i++){
      int c = wave + i*4;
      stage16(&A [(size_t)(m0 + c*16 + lr)*512 + k0 + lcs], &As[buf][c*16*32]);
      stage16(&Bt[(size_t)(n0 + c*16 + lr)*512 + k0 + lcs], &Bs[buf][c*16*32]);
    }
  };
  stage_tile(0, 0);
  stage_tile(32, 1);
  for (int it=0; it<16; it++){
    int cur = it%3;
    if (it<14){
      stage_tile((it+2)*32, (it+2)%3);
      asm volatile("s_waitcnt vmcnt(8)" ::: "memory");
    } else if (it==14){
      asm volatile("s_waitcnt vmcnt(4)" ::: "memory");
    } else {
      asm volatile("s_waitcnt vmcnt(0)" ::: "memory");
    }
    __syncthreads();
    bf16x8 a[4], b[4];
    #pragma unroll
    for (int mi=0;mi<4;mi++) a[mi] = *reinterpret_cast<const bf16x8*>(&As[cur][swz_ld(wm*64+mi*16+(lane&15), lane>>4)]);
    #pragma unroll
    for (int ni=0;ni<4;ni++) b[ni] = *reinterpret_cast<const bf16x8*>(&Bs[cur][swz_ld(wn*64+ni*16+(lane&15), lane>>4)]);
    #pragma unroll
    for (int mi=0;mi<4;mi++)
      #pragma unroll
      for (int ni=0;ni<4;ni++)
        acc[mi][ni] = mfma16(a[mi], b[ni], acc[mi][ni]);
    __syncthreads();
  }
  #pragma unroll
  for (int mi=0;mi<4;mi++){
    int gr0 = m0 + wm*64 + mi*16 + ((lane>>4)<<2);
    #pragma unroll
    for (int ni=0;ni<4;ni++){
      int gc = n0 + wn*64 + ni*16 + (lane&15);
      float bv = bo[gc];
      #pragma unroll
      for (int r=0;r<4;r++){
        int row = gr0 + r;
        out[(size_t)row*512 + gc] = acc[mi][ni][r] + bv + x[(size_t)row*512 + gc];
      }
    }
  }
}

extern "C" void kernel_launch(void* const* d_in, const int* in_sizes, int n_in,
                              void* d_out, int out_size, void* d_ws, size_t ws_size,
                              hipStream_t stream) {
  (void)in_sizes; (void)n_in; (void)out_size;
  const float* x     = (const float*)d_in[0];
  const float* ln_g  = (const float*)d_in[1];
  const float* ln_b  = (const float*)d_in[2];
  const float* w_qkv = (const float*)d_in[3];
  const float* w_out = (const float*)d_in[4];
  const float* b_out = (const float*)d_in[5];
  const float* res_k = (const float*)d_in[6];
  float* out = (float*)d_out;

  char* ws = (char*)d_ws;
  size_t off = 0;
  auto alloc = [&](size_t n)->char*{ char* r = ws + off; off += (n + 255) & ~(size_t)255; return r; };

  u16* xn     = (u16*)alloc((size_t)TOK*512*2);      // cc aliases this after k_qkv
  u16* cc     = xn;
  u16* wqkvt  = (u16*)alloc(1536*512*2);
  u16* woutt  = (u16*)alloc(512*512*2);
  u16* qb     = (u16*)alloc((size_t)BH*N_*64*2);
  u16* kb     = (u16*)alloc((size_t)BH*N_*64*2);
  u16* vt     = (u16*)alloc((size_t)BH*N_*64*2);
  u16* ql     = (u16*)alloc((size_t)BH*256*64*2);
  u16* kl     = (u16*)alloc((size_t)BH*256*64*2);
  float* X    = (float*)alloc((size_t)BH*65536*4);   // A1t aliases this after pinvinit
  float* Xt   = (float*)alloc((size_t)BH*65536*4);   // B1 aliases this after pinvinit
  float* sc   = (float*)alloc(32*4);
  u16* Xhi    = (u16*)alloc((size_t)BH*65536*2);
  u16* Xlo    = (u16*)alloc((size_t)BH*65536*2);
  u16* Znh    = (u16*)alloc((size_t)BH*65536*2);
  u16* Znl    = (u16*)alloc((size_t)BH*65536*2);
  u16* Zth    = (u16*)alloc((size_t)BH*65536*2);
  u16* Ztl    = (u16*)alloc((size_t)BH*65536*2);
  u16* B2h    = (u16*)alloc((size_t)BH*65536*2);
  u16* B2l    = (u16*)alloc((size_t)BH*65536*2);
  u16* res_t  = (u16*)alloc((size_t)BH*64*N_*2);
  size_t need = off;
  if (ws_size < need) return;   // diagnostic guard: clean fail instead of OOB abort

  u16* A1th = (u16*)X;
  u16* A1tl = (u16*)X + (size_t)BH*65536;
  u16* B1h  = (u16*)Xt;
  u16* B1l  = (u16*)Xt + (size_t)BH*65536;

  // scratch carved from d_out (fully overwritten by k_out at the end)
  char* ob = (char*)d_out;
  float* part  = (float*)(ob);                        // 16*32*256*64*4 = 33,554,432
  float* lpart = (float*)(ob + 33554432);             // 16*32*256*4   =    524,288
  float* wbuf  = (float*)(ob + 34078720);             // 32*256*64*4   =  2,097,152
  u16*   w2t   = (u16*)  (ob + 36175872);             // 32*64*256*2   =  1,048,576

  k_prep<<<dim3(512),256,0,stream>>>(w_qkv, w_out, wqkvt, woutt);
  k_ln<<<dim3(TOK),256,0,stream>>>(x, ln_g, ln_b, xn);
  k_qkv<<<dim3(256,12),256,0,stream>>>(xn, wqkvt, qb, kb, vt);
  k_land<<<dim3(8192),64,0,stream>>>(qb, kb, ql, kl);
  k_attn2<<<dim3(8192),256,0,stream>>>(ql, kl, X, Xt);
  k_pinvstats<<<dim3(32),256,0,stream>>>(X, sc);
  k_pinvinit<<<dim3(8192),256,0,stream>>>(X, Xt, sc, Xhi, Xlo, Znh, Znl, Zth, Ztl);

  dim3 gmm(4,4,32);
  for (int it=0; it<6; it++){
    // A1 = X @ Z   (written transposed)
    k_mmhl<1><<<gmm,256,0,stream>>>(Xhi,Xlo, Zth,Ztl, A1th,A1tl,
        nullptr,nullptr,nullptr,nullptr,nullptr,nullptr, nullptr,nullptr);
    // B1 = Z @ A1
    k_mmhl<0><<<gmm,256,0,stream>>>(Znh,Znl, A1th,A1tl, B1h,B1l,
        nullptr,nullptr,nullptr,nullptr,nullptr,nullptr, nullptr,nullptr);
    // B2 = B1 @ A1
    k_mmhl<0><<<gmm,256,0,stream>>>(B1h,B1l, A1th,A1tl, B2h,B2l,
        nullptr,nullptr,nullptr,nullptr,nullptr,nullptr, nullptr,nullptr);
    // z' = 0.25(13Z - 15B1 + 7B2 - B2@A1), Z updated in place (epilogue-local reads)
    k_mmhl<2><<<gmm,256,0,stream>>>(B2h,B2l, A1th,A1tl, Znh,Znl,
        Znh,Znl, B1h,B1l, B2h,B2l, Zth,Ztl);
  }

  k_flashw<<<dim3(16,32),256,0,stream>>>(ql, kb, vt, part, lpart);
  k_wfin<<<dim3(2048),256,0,stream>>>(part, lpart, wbuf);
  k_w2<<<dim3(8192),64,0,stream>>>(Znh, Znl, wbuf, w2t);
  k_conv<<<dim3(4,64,32),256,0,stream>>>(vt, res_k, res_t);
  k_attn1<<<dim3(64,32),256,0,stream>>>(qb, kl, w2t, res_t, cc);
  k_out<<<dim3(256,4),256,0,stream>>>(cc, woutt, b_out, x, out);
}